// Round 1
// baseline (4000.705 us; speedup 1.0000x reference)
//
#include <hip/hip_runtime.h>

#define C  64
#define KK 27
#define BB 4

// ws layout (float offsets):
//      0 : pooled[BB*C]        (256)
//    256 : counts[BB]          (4)
//    260 : gate[BB*C]          (256)
//    516 : bnscale[C]          (64)
//    580 : bnshift[C]          (64)
//   1024 : W1g[BB*KK*C*C]      (442368)
// 443392 : h[N*C]

__global__ __launch_bounds__(256) void init_ws(float* ws) {
  int t = blockIdx.x * 256 + threadIdx.x;
  if (t < 260) ws[t] = 0.f;
}

__global__ __launch_bounds__(256) void pool_kernel(
    const float* __restrict__ x, const int* __restrict__ bidx,
    float* __restrict__ pooled, float* __restrict__ counts, int N)
{
  const int PTS = 4096;
  int base = blockIdx.x * PTS;
  int col = threadIdx.x & 63;
  int row = threadIdx.x >> 6;            // 0..3
  float a0 = 0.f, a1 = 0.f, a2 = 0.f, a3 = 0.f;
  int   c0 = 0, c1 = 0, c2 = 0, c3 = 0;
  for (int i = row; i < PTS; i += 4) {
    int n = base + i;
    if (n >= N) break;
    int b = bidx[n];
    float v = x[((size_t)n << 6) + col];
    if (b == 0)      { a0 += v; c0++; }
    else if (b == 1) { a1 += v; c1++; }
    else if (b == 2) { a2 += v; c2++; }
    else             { a3 += v; c3++; }
  }
  __shared__ float red[BB][4][C];
  __shared__ int   cred[BB][4];
  red[0][row][col] = a0; red[1][row][col] = a1;
  red[2][row][col] = a2; red[3][row][col] = a3;
  if (col == 0) { cred[0][row] = c0; cred[1][row] = c1; cred[2][row] = c2; cred[3][row] = c3; }
  __syncthreads();
  {
    int b = threadIdx.x >> 6, c = threadIdx.x & 63;
    float s = red[b][0][c] + red[b][1][c] + red[b][2][c] + red[b][3][c];
    if (s != 0.f) atomicAdd(&pooled[b * C + c], s);
  }
  if (threadIdx.x < BB) {
    int b = threadIdx.x;
    int s = cred[b][0] + cred[b][1] + cred[b][2] + cred[b][3];
    if (s) atomicAdd(&counts[b], (float)s);
  }
}

__global__ __launch_bounds__(256) void gate_kernel(
    const float* __restrict__ pooled, const float* __restrict__ counts,
    const float* __restrict__ w_fc1, const float* __restrict__ b_fc1,
    const float* __restrict__ w_fc2, const float* __restrict__ b_fc2,
    const float* __restrict__ bn_gamma, const float* __restrict__ bn_beta,
    const float* __restrict__ bn_mean, const float* __restrict__ bn_var,
    float* __restrict__ gate, float* __restrict__ bnscale, float* __restrict__ bnshift)
{
  __shared__ float mean[BB * C];
  __shared__ float hh[BB * 16];
  int t = threadIdx.x;
  { int b = t >> 6; mean[t] = pooled[t] / counts[b]; }
  __syncthreads();
  if (t < BB * 16) {
    int b = t >> 4, r = t & 15;
    float s = b_fc1[r];
    for (int c = 0; c < C; ++c) s += mean[b * C + c] * w_fc1[c * 16 + r];
    hh[t] = fmaxf(s, 0.f);
  }
  __syncthreads();
  {
    int b = t >> 6, c = t & 63;
    float s = b_fc2[c];
    for (int r = 0; r < 16; ++r) s += hh[b * 16 + r] * w_fc2[r * 64 + c];
    gate[t] = 1.f / (1.f + expf(-s));
  }
  if (t < C) {
    float sc = bn_gamma[t] * rsqrtf(bn_var[t] + 1e-5f);
    bnscale[t] = sc;
    bnshift[t] = bn_beta[t] - bn_mean[t] * sc;
  }
}

// W1g[b][k][ci][co] = gate[b][ci] * W1[k][ci][co]
__global__ __launch_bounds__(256) void scale_w1(
    const float* __restrict__ w1, const float* __restrict__ gate,
    float* __restrict__ w1g)
{
  int b = blockIdx.x & 3, k = blockIdx.x >> 2;
  const float* src = w1 + ((size_t)k << 12);
  float* dst = w1g + (((size_t)(b * KK + k)) << 12);
  const float* g = gate + (b << 6);
  for (int it = 0; it < 16; ++it) {
    int pos = it * 256 + threadIdx.x;
    int ci = pos >> 6;
    dst[pos] = g[ci] * src[pos];
  }
}

// One wave per point, lane = output channel. Wave-uniform skip of invalid offsets.
// MODE 0: conv1 (per-batch gated W, epilogue BN+ReLU)   MODE 1: conv2 (epilogue +bias)
template <int MODE>
__global__ __launch_bounds__(256) void spconv_kernel(
    const float* __restrict__ x, const int* __restrict__ nbr,
    const int* __restrict__ bidx, const float* __restrict__ W,
    const float* __restrict__ ep_a, const float* __restrict__ ep_b,
    float* __restrict__ out, int N)
{
  int wid = (int)((blockIdx.x * 256u + threadIdx.x) >> 6);
  if (wid >= N) return;
  int lane = threadIdx.x & 63;
  int n = __builtin_amdgcn_readfirstlane(wid);
  const float* Wb = W;
  if (MODE == 0) {
    int b = __builtin_amdgcn_readfirstlane(bidx[n]);
    Wb += (size_t)b * (KK * C * C);
  }
  float acc = 0.f;
#pragma unroll 1
  for (int k = 0; k < KK; ++k) {
    int idx = __builtin_amdgcn_readfirstlane(nbr[(size_t)k * N + n]);
    if (idx < 0) continue;
    const float* xr = x + ((size_t)idx << 6);
    const float* wr = Wb + (k << 12) + lane;
#pragma unroll
    for (int ci = 0; ci < C; ++ci) {
      acc = fmaf(xr[ci], wr[ci << 6], acc);
    }
  }
  float r;
  if (MODE == 0) r = fmaxf(fmaf(acc, ep_a[lane], ep_b[lane]), 0.f);
  else           r = acc + ep_b[lane];
  out[((size_t)n << 6) + lane] = r;
}

extern "C" void kernel_launch(void* const* d_in, const int* in_sizes, int n_in,
                              void* d_out, int out_size, void* d_ws, size_t ws_size,
                              hipStream_t stream) {
  const float* feats   = (const float*)d_in[0];
  const int*   nbr     = (const int*)  d_in[1];
  const int*   bidx    = (const int*)  d_in[2];
  const float* w_fc1   = (const float*)d_in[3];
  const float* b_fc1   = (const float*)d_in[4];
  const float* w_fc2   = (const float*)d_in[5];
  const float* b_fc2   = (const float*)d_in[6];
  const float* w_conv1 = (const float*)d_in[7];
  const float* bn_gamma= (const float*)d_in[8];
  const float* bn_beta = (const float*)d_in[9];
  const float* bn_mean = (const float*)d_in[10];
  const float* bn_var  = (const float*)d_in[11];
  const float* w_conv2 = (const float*)d_in[12];
  const float* b_conv2 = (const float*)d_in[13];

  int N = in_sizes[0] / C;
  float* ws      = (float*)d_ws;
  float* pooled  = ws;
  float* counts  = ws + 256;
  float* gate    = ws + 260;
  float* bnscale = ws + 516;
  float* bnshift = ws + 580;
  float* w1g     = ws + 1024;
  float* h       = ws + 1024 + BB * KK * C * C;
  float* out     = (float*)d_out;

  hipLaunchKernelGGL(init_ws, dim3(2), dim3(256), 0, stream, ws);
  hipLaunchKernelGGL(pool_kernel, dim3((N + 4095) / 4096), dim3(256), 0, stream,
                     feats, bidx, pooled, counts, N);
  hipLaunchKernelGGL(gate_kernel, dim3(1), dim3(256), 0, stream,
                     pooled, counts, w_fc1, b_fc1, w_fc2, b_fc2,
                     bn_gamma, bn_beta, bn_mean, bn_var, gate, bnscale, bnshift);
  hipLaunchKernelGGL(scale_w1, dim3(KK * BB), dim3(256), 0, stream,
                     w_conv1, gate, w1g);
  hipLaunchKernelGGL((spconv_kernel<0>), dim3((N + 3) / 4), dim3(256), 0, stream,
                     feats, nbr, bidx, w1g, bnscale, bnshift, h, N);
  hipLaunchKernelGGL((spconv_kernel<1>), dim3((N + 3) / 4), dim3(256), 0, stream,
                     h, nbr, bidx, w_conv2, nullptr, b_conv2, out, N);
}